// Round 8
// baseline (311.523 us; speedup 1.0000x reference)
//
#include <hip/hip_runtime.h>
#include <math.h>

#define N_IMG 16
#define N_CLS 80
#define K_PRE 1000
#define K_POST 100
#define NPAIR 48
#define NBIN 4096
#define BSHIFT 20          // 12-bit bin = key >> 20
#define CAP 4096
#define IDXM 0xFFFFFu      // 20-bit packed (loc*80+c) index
#define CHUNK 256
#define CPB 20             // classes per block
#define BPI 56             // blocks per image: lvl0 10*4, lvl1 3*4, lvl2 1*4
#define NWRD (NBIN / 2)
#define SEG 1024           // sort segment size

// ---- workspace layout (bytes) ----
#define CNT_OFF    0                 // uint[48]                 -> 192
#define TBIN_OFF   192               // uint[48]                 -> 384
#define H16_OFF    384               // u32[896*2048]            -> 7340416
#define LIST_OFF   7340416           // u64[48*4096]             -> 8913280
#define CANDF_OFF  8913280           // uint[48000]              -> 9105280
#define CANDS_OFF  9105280           // float[48000]             -> 9297280
#define DBOX_OFF   9297280           // float4[48000] (16B-al)   -> 10065280
#define DCLS_OFF   10065280          // int[48000]               -> 10257280

__device__ __forceinline__ float sigm(float x) { return 1.0f / (1.0f + __expf(-x)); }
__device__ __forceinline__ int lvl_hw(int lvl) { return lvl == 0 ? 10000 : (lvl == 1 ? 2500 : 625); }

__device__ __forceinline__ void blk_map(int bx, int& lvl, int& locb, int& cg) {
    if (bx < 40)      { lvl = 0; locb = bx >> 2;        cg = bx & 3; }
    else if (bx < 52) { lvl = 1; locb = (bx - 40) >> 2; cg = bx & 3; }
    else              { lvl = 2; locb = 0;              cg = bx - 52; }
}

// ---------------- scan 1: private u16-slice histogram ----------------
__global__ __launch_bounds__(256) void hist_k(
        const float* __restrict__ cls0, const float* __restrict__ cls1, const float* __restrict__ cls2,
        const float* __restrict__ ctr0, const float* __restrict__ ctr1, const float* __restrict__ ctr2,
        unsigned* __restrict__ h16) {
    __shared__ unsigned lh[NBIN];
    const int img = blockIdx.y, bx = blockIdx.x;
    int lvl, locb, cg; blk_map(bx, lvl, locb, cg);
    const float* cls = lvl == 0 ? cls0 : (lvl == 1 ? cls1 : cls2);
    const float* ctr = lvl == 0 ? ctr0 : (lvl == 1 ? ctr1 : ctr2);
    const int HW = lvl_hw(lvl);
    for (int i = threadIdx.x; i < NBIN; i += 256) lh[i] = 0;
    __syncthreads();
    const int fi = locb * 256 + threadIdx.x;
    const int nf4 = HW >> 2;
    const float* clsI = cls + (size_t)img * N_CLS * HW + (size_t)cg * CPB * HW;
    const float* ctrI = ctr + (size_t)img * HW;
    if (fi < nf4) {
        const int base = fi * 4;
        float4 cv = *(const float4*)(ctrI + base);
        float s0 = sigm(cv.x), s1 = sigm(cv.y), s2 = sigm(cv.z), s3 = sigm(cv.w);
        #pragma unroll 5
        for (int c = 0; c < CPB; ++c) {
            float4 v = *(const float4*)(clsI + (size_t)c * HW + base);
            float cp;
            cp = sigm(v.x); if (cp > 0.05f) atomicAdd(&lh[__float_as_uint(cp * s0) >> BSHIFT], 1u);
            cp = sigm(v.y); if (cp > 0.05f) atomicAdd(&lh[__float_as_uint(cp * s1) >> BSHIFT], 1u);
            cp = sigm(v.z); if (cp > 0.05f) atomicAdd(&lh[__float_as_uint(cp * s2) >> BSHIFT], 1u);
            cp = sigm(v.w); if (cp > 0.05f) atomicAdd(&lh[__float_as_uint(cp * s3) >> BSHIFT], 1u);
        }
    } else if (fi == nf4) {
        for (int k = 0; k < (HW & 3); ++k) {
            int loc = nf4 * 4 + k;
            float cs = sigm(ctrI[loc]);
            for (int c = 0; c < CPB; ++c) {
                float cp = sigm(clsI[(size_t)c * HW + loc]);
                if (cp > 0.05f) atomicAdd(&lh[__float_as_uint(cp * cs) >> BSHIFT], 1u);
            }
        }
    }
    __syncthreads();
    unsigned* sp = h16 + (size_t)(img * BPI + bx) * NWRD;
    for (int w = threadIdx.x; w < NWRD; w += 256)
        sp[w] = (lh[2 * w] & 0xFFFFu) | (lh[2 * w + 1] << 16);
}

// ---------------- fused slice-sum + threshold bin + cnt zeroing ----------------
__global__ __launch_bounds__(256) void scan2_k(const unsigned* __restrict__ h16,
                                               unsigned* __restrict__ tbin,
                                               unsigned* __restrict__ cnt) {
    __shared__ unsigned hs[NBIN];
    __shared__ unsigned csum[256];
    __shared__ unsigned suf[256];
    __shared__ unsigned res;
    const int p = blockIdx.x, t = threadIdx.x;
    const int img = p / 3, lvl = p % 3;
    const int sb = img * BPI + (lvl == 0 ? 0 : (lvl == 1 ? 40 : 52));
    const int ns = lvl == 0 ? 40 : (lvl == 1 ? 12 : 4);
    const unsigned* s0 = h16 + (size_t)sb * NWRD;
    for (int w = t; w < NWRD; w += 256) {
        unsigned lo = 0, hi = 0;
        for (int s = 0; s < ns; ++s) {
            unsigned u = s0[(size_t)s * NWRD + w];
            lo += u & 0xFFFFu; hi += u >> 16;
        }
        hs[2 * w] = lo; hs[2 * w + 1] = hi;
    }
    if (t == 0) { res = 0; cnt[p] = 0; }
    __syncthreads();
    unsigned ms = 0;
    for (int j = 0; j < 16; ++j) ms += hs[t * 16 + j];
    csum[t] = ms;
    __syncthreads();
    if (t == 0) {
        unsigned a = 0;
        for (int i = 255; i >= 0; --i) { suf[i] = a; a += csum[i]; }
    }
    __syncthreads();
    unsigned A = suf[t];
    for (int j = 15; j >= 0; --j) {
        unsigned c = hs[t * 16 + j];
        if (A < K_PRE && A + c >= K_PRE) res = (unsigned)(t * 16 + j);
        A += c;
    }
    __syncthreads();
    if (t == 0) tbin[p] = res;
}

// ---------------- scan 2: LDS-staged compaction ----------------
__global__ __launch_bounds__(256) void compact_k(
        const float* __restrict__ cls0, const float* __restrict__ cls1, const float* __restrict__ cls2,
        const float* __restrict__ ctr0, const float* __restrict__ ctr1, const float* __restrict__ ctr2,
        const unsigned* __restrict__ tbin, unsigned* __restrict__ cnt, unsigned long long* __restrict__ list) {
    __shared__ unsigned long long buf[CAP];
    __shared__ unsigned lcnt, gbase;
    const int img = blockIdx.y, bx = blockIdx.x;
    int lvl, locb, cg; blk_map(bx, lvl, locb, cg);
    const float* cls = lvl == 0 ? cls0 : (lvl == 1 ? cls1 : cls2);
    const float* ctr = lvl == 0 ? ctr0 : (lvl == 1 ? ctr1 : ctr2);
    const int HW = lvl_hw(lvl);
    const int p = img * 3 + lvl;
    const unsigned Tb = tbin[p];
    if (threadIdx.x == 0) lcnt = 0;
    __syncthreads();
    const int fi = locb * 256 + threadIdx.x;
    const int nf4 = HW >> 2;
    const float* clsI = cls + (size_t)img * N_CLS * HW + (size_t)cg * CPB * HW;
    const float* ctrI = ctr + (size_t)img * HW;
    const int c0 = cg * CPB;
    if (fi < nf4) {
        const int base = fi * 4;
        float4 cv = *(const float4*)(ctrI + base);
        float css[4] = {sigm(cv.x), sigm(cv.y), sigm(cv.z), sigm(cv.w)};
        #pragma unroll 5
        for (int c = 0; c < CPB; ++c) {
            float4 v = *(const float4*)(clsI + (size_t)c * HW + base);
            float cps[4] = {sigm(v.x), sigm(v.y), sigm(v.z), sigm(v.w)};
            #pragma unroll
            for (int k = 0; k < 4; ++k) {
                if (cps[k] > 0.05f) {
                    unsigned key = __float_as_uint(cps[k] * css[k]);
                    if ((key >> BSHIFT) >= Tb) {
                        unsigned slot = atomicAdd(&lcnt, 1u);
                        unsigned idx = (unsigned)((base + k) * N_CLS + c0 + c);
                        if (slot < CAP)
                            buf[slot] = ((unsigned long long)key << 20) | (unsigned long long)(IDXM ^ idx);
                    }
                }
            }
        }
    } else if (fi == nf4) {
        for (int k = 0; k < (HW & 3); ++k) {
            int loc = nf4 * 4 + k;
            float cs = sigm(ctrI[loc]);
            for (int c = 0; c < CPB; ++c) {
                float cp = sigm(clsI[(size_t)c * HW + loc]);
                if (cp > 0.05f) {
                    unsigned key = __float_as_uint(cp * cs);
                    if ((key >> BSHIFT) >= Tb) {
                        unsigned slot = atomicAdd(&lcnt, 1u);
                        unsigned idx = (unsigned)(loc * N_CLS + c0 + c);
                        if (slot < CAP)
                            buf[slot] = ((unsigned long long)key << 20) | (unsigned long long)(IDXM ^ idx);
                    }
                }
            }
        }
    }
    __syncthreads();
    unsigned n = lcnt; if (n > CAP) n = CAP;
    if (threadIdx.x == 0 && n) gbase = atomicAdd(&cnt[p], n);
    __syncthreads();
    if (n) {
        unsigned gb = gbase;
        unsigned long long* lp = list + (size_t)p * CAP;
        for (unsigned i = threadIdx.x; i < n; i += 256) {
            unsigned g = gb + i;
            if (g < CAP) lp[g] = buf[i];
        }
    }
}

// ---------------- fused: 4-segment bitonic sort + merge-path top-1000 ----------------
__global__ __launch_bounds__(1024) void sortmerge_k(const unsigned* __restrict__ cnt,
                                                    const unsigned long long* __restrict__ list,
                                                    unsigned* __restrict__ candF, float* __restrict__ candS) {
    __shared__ unsigned long long sk[CAP];   // 32 KB
    __shared__ float oS[K_PRE];
    __shared__ unsigned oF[K_PRE];
    const int p = blockIdx.x, t = threadIdx.x;
    int n = (int)cnt[p]; if (n > CAP) n = CAP;
    const unsigned long long* lp = list + (size_t)p * CAP;
    for (int i = t; i < CAP; i += 1024) sk[i] = (i < n) ? lp[i] : 0ull;
    if (t < K_PRE) { oS[t] = -1.0f; oF[t] = 0u; }
    __syncthreads();
    for (int seg = 0; seg < 4; ++seg) {
        const int b = seg << 10;
        unsigned long long v = sk[b + t];
        for (int k = 2; k <= SEG; k <<= 1) {
            for (int j = k >> 1; j >= 64; j >>= 1) {
                sk[b + t] = v;
                __syncthreads();
                unsigned long long o = sk[b + (t ^ j)];
                __syncthreads();
                bool mx = (((t & k) == 0) == ((t & j) == 0));
                v = mx ? (v > o ? v : o) : (v < o ? v : o);
            }
            int j0 = (k >> 1) < 64 ? (k >> 1) : 32;
            for (int j = j0; j >= 1; j >>= 1) {
                unsigned long long o = __shfl_xor(v, j);
                bool mx = (((t & k) == 0) == ((t & j) == 0));
                v = mx ? (v > o ? v : o) : (v < o ? v : o);
            }
        }
        sk[b + t] = v;
        __syncthreads();
    }
    if (t < K_PRE) {
        #pragma unroll
        for (int q = 0; q < 4; ++q) {
            unsigned long long v = sk[(q << 10) | t];
            if (v == 0ull) continue;
            int rank = t;
            #pragma unroll
            for (int s2 = 0; s2 < 4; ++s2) {
                if (s2 == q) continue;
                const unsigned long long* seg2 = sk + (s2 << 10);
                int lo = 0, hi = SEG;
                while (lo < hi) {
                    int m = (lo + hi) >> 1;
                    if (seg2[m] > v) lo = m + 1; else hi = m;
                }
                rank += lo;
            }
            if (rank < K_PRE) {
                oS[rank] = __uint_as_float((unsigned)(v >> 20));
                oF[rank] = IDXM ^ (unsigned)(v & IDXM);
            }
        }
    }
    __syncthreads();
    if (t < K_PRE) { candS[p * K_PRE + t] = oS[t]; candF[p * K_PRE + t] = oF[t]; }
}

// ---------------- parallel box decode ----------------
__global__ __launch_bounds__(256) void decode_k(
        const float* __restrict__ loc0, const float* __restrict__ loc1, const float* __restrict__ loc2,
        const float* __restrict__ reg0, const float* __restrict__ reg1, const float* __restrict__ reg2,
        const unsigned* __restrict__ candF, const float* __restrict__ candS,
        float4* __restrict__ dbox, int* __restrict__ dcls) {
    int i = blockIdx.x * blockDim.x + threadIdx.x;
    if (i >= NPAIR * K_PRE) return;
    int p = i / K_PRE, slot = i % K_PRE;
    int img = p / 3, lvl = p % 3;
    int o = img * 3000 + lvl * K_PRE + slot;
    float s = candS[i];
    if (!(s > 0.0f)) { dbox[o] = make_float4(0.f, 0.f, 0.f, 0.f); dcls[o] = 0; return; }
    const float* locs = lvl == 0 ? loc0 : (lvl == 1 ? loc1 : loc2);
    const float* rg = lvl == 0 ? reg0 : (lvl == 1 ? reg1 : reg2);
    const int HW = lvl_hw(lvl);
    const float st = lvl == 0 ? 8.f : (lvl == 1 ? 16.f : 32.f);
    unsigned fi = candF[i];
    int loc = (int)(fi / (unsigned)N_CLS);
    int c = (int)(fi % (unsigned)N_CLS) + 1;
    const float* rb = rg + (size_t)img * 4 * HW;
    float lv = rb[loc] * st, tv = rb[HW + loc] * st;
    float rv = rb[2 * HW + loc] * st, bv = rb[3 * HW + loc] * st;
    float x = locs[2 * loc], y = locs[2 * loc + 1];
    float x1 = fminf(fmaxf(x - lv, 0.f), 800.f);
    float y1 = fminf(fmaxf(y - tv, 0.f), 800.f);
    float x2 = fminf(fmaxf(x + rv, 0.f), 800.f);
    float y2 = fminf(fmaxf(y + bv, 0.f), 800.f);
    dbox[o] = make_float4(x1, y1, x2, y2);
    dcls[o] = c;
}

// ---------------- merge 3 sorted lists + bitmask greedy NMS (1024 thr) ----------------
__global__ __launch_bounds__(1024) void nms_k(
        const float4* __restrict__ dbox, const int* __restrict__ dcls,
        const float* __restrict__ candS, float* __restrict__ out) {
    __shared__ float skey[3000];
    __shared__ unsigned short sidx[3000];
    __shared__ float4 sbox[CHUNK], obox[CHUNK];
    __shared__ float sarea[CHUNK], sscor[CHUNK];
    __shared__ int scls[CHUNK];
    __shared__ __align__(16) unsigned adjW[CHUNK * 8];
    __shared__ unsigned aliveW[8];
    __shared__ float4 kbox[K_POST], kobox[K_POST];
    __shared__ float karea[K_POST], kscor[K_POST];
    __shared__ int kcls[K_POST];
    __shared__ int s_keptn, s_done;
    const int img = blockIdx.x, tid = threadIdx.x;
    if (tid == 0) { s_keptn = 0; s_done = 0; }
    for (int i = tid; i < 3000; i += 1024) skey[i] = candS[img * 3000 + i];
    __syncthreads();
    // rank-merge: order = (score desc, lvl, slot) == reference concat + argmax tie rule
    for (int e = tid; e < 3000; e += 1024) {
        int l = e >= 2000 ? 2 : (e >= 1000 ? 1 : 0);
        int slot = e - l * 1000;
        float s = skey[e];
        int rank = slot;
        for (int l2 = 0; l2 < 3; ++l2) {
            if (l2 == l) continue;
            const float* kb = skey + l2 * 1000;
            const bool eq = l2 < l;
            int lo = 0, hi = 1000;
            while (lo < hi) {
                int m = (lo + hi) >> 1;
                float v = kb[m];
                bool go = eq ? (v >= s) : (v > s);
                lo = go ? m + 1 : lo;
                hi = go ? hi : m;
            }
            rank += lo;
        }
        sidx[rank] = (unsigned short)e;
    }
    __syncthreads();
    for (int base = 0; base < 3000; base += CHUNK) {
        if (s_done) break;
        const int kn0 = s_keptn;
        if (tid < 8) aliveW[tid] = 0u;
        __syncthreads();
        if (tid < CHUNK) {
            const int q = tid;
            const int r = base + q;
            float4 bx = make_float4(0.f, 0.f, 0.f, 0.f), ox = bx;
            float ar = 0.f, ssc = 0.f; int cl = 0, alive = 0;
            if (r < 3000) {
                int e = sidx[r];
                float s = skey[e];
                if (s > 0.f) {
                    bx = dbox[img * 3000 + e];
                    cl = dcls[img * 3000 + e];
                    float off = (float)cl * 4096.0f;
                    ox = make_float4(bx.x + off, bx.y + off, bx.z + off, bx.w + off);
                    ar = (ox.z - ox.x) * (ox.w - ox.y);
                    ssc = sqrtf(s);
                    alive = 1;
                    for (int k = 0; k < kn0; ++k) {
                        float4 kb = kobox[k];
                        float xx1 = fmaxf(kb.x, ox.x), yy1 = fmaxf(kb.y, ox.y);
                        float xx2 = fminf(kb.z, ox.z), yy2 = fminf(kb.w, ox.w);
                        float inter = fmaxf(xx2 - xx1, 0.f) * fmaxf(yy2 - yy1, 0.f);
                        float iou = inter / (ar + karea[k] - inter + 1e-9f);
                        if (iou > 0.6f) { alive = 0; break; }
                    }
                }
            }
            sbox[q] = bx; obox[q] = ox; sarea[q] = ar; sscor[q] = ssc; scls[q] = cl;
            if (alive) atomicOr(&aliveW[q >> 5], 1u << (q & 31));
        }
        __syncthreads();
        {
            const int g = tid >> 8;
            const int i = tid & 255;
            float4 bi = obox[i];
            float ai = sarea[i];
            #pragma unroll
            for (int ww = 0; ww < 2; ++ww) {
                const int w = g * 2 + ww;
                unsigned bb = 0;
                int j0 = w << 5;
                int js = j0 > i + 1 ? j0 : i + 1;
                for (int j = js; j < j0 + 32; ++j) {
                    float4 bj = obox[j];
                    float xx1 = fmaxf(bi.x, bj.x), yy1 = fmaxf(bi.y, bj.y);
                    float xx2 = fminf(bi.z, bj.z), yy2 = fminf(bi.w, bj.w);
                    float inter = fmaxf(xx2 - xx1, 0.f) * fmaxf(yy2 - yy1, 0.f);
                    float iou = inter / (sarea[j] + ai - inter + 1e-9f);
                    if (iou > 0.6f) bb |= 1u << (j & 31);
                }
                adjW[i * 8 + w] = bb;
            }
        }
        __syncthreads();
        if (tid < 64) {   // wave-0 resolve: replicated alive mask, no ballot/shfl in chain
            unsigned aw[8];
            #pragma unroll
            for (int w = 0; w < 8; ++w) aw[w] = aliveW[w];
            int kn = kn0;
            while (kn < K_POST) {
                int e = -1;
                #pragma unroll
                for (int w = 7; w >= 0; --w)
                    if (aw[w]) e = (w << 5) + (__ffs(aw[w]) - 1);
                if (e < 0) break;
                const uint4* rp = (const uint4*)&adjW[e * 8];
                uint4 r0 = rp[0], r1 = rp[1];
                unsigned ew = (unsigned)e >> 5, eb = 1u << (e & 31);
                aw[0] &= ~(r0.x | (ew == 0 ? eb : 0u));
                aw[1] &= ~(r0.y | (ew == 1 ? eb : 0u));
                aw[2] &= ~(r0.z | (ew == 2 ? eb : 0u));
                aw[3] &= ~(r0.w | (ew == 3 ? eb : 0u));
                aw[4] &= ~(r1.x | (ew == 4 ? eb : 0u));
                aw[5] &= ~(r1.y | (ew == 5 ? eb : 0u));
                aw[6] &= ~(r1.z | (ew == 6 ? eb : 0u));
                aw[7] &= ~(r1.w | (ew == 7 ? eb : 0u));
                if (tid == 0) {
                    kbox[kn] = sbox[e]; kobox[kn] = obox[e];
                    karea[kn] = sarea[e]; kscor[kn] = sscor[e]; kcls[kn] = scls[e];
                }
                kn++;
            }
            if (tid == 0) { s_keptn = kn; s_done = (kn >= K_POST) ? 1 : 0; }
        }
        __syncthreads();
    }
    const int kn = s_keptn;
    if (tid < K_POST) {
        float4 b = make_float4(0.f, 0.f, 0.f, 0.f);
        float sc = 0.f, cl = 0.f, kp = 0.f;
        if (tid < kn) { b = kbox[tid]; sc = kscor[tid]; cl = (float)kcls[tid]; kp = 1.0f; }
        float* bo = out + (size_t)(img * K_POST + tid) * 4;
        bo[0] = b.x; bo[1] = b.y; bo[2] = b.z; bo[3] = b.w;
        out[N_IMG * K_POST * 4 + img * K_POST + tid] = sc;
        out[N_IMG * K_POST * 5 + img * K_POST + tid] = cl;
        out[N_IMG * K_POST * 6 + img * K_POST + tid] = kp;
    }
}

extern "C" void kernel_launch(void* const* d_in, const int* in_sizes, int n_in,
                              void* d_out, int out_size, void* d_ws, size_t ws_size,
                              hipStream_t stream) {
    const float* loc0 = (const float*)d_in[0];
    const float* cls0 = (const float*)d_in[1];
    const float* reg0 = (const float*)d_in[2];
    const float* ctr0 = (const float*)d_in[3];
    const float* loc1 = (const float*)d_in[4];
    const float* cls1 = (const float*)d_in[5];
    const float* reg1 = (const float*)d_in[6];
    const float* ctr1 = (const float*)d_in[7];
    const float* loc2 = (const float*)d_in[8];
    const float* cls2 = (const float*)d_in[9];
    const float* reg2 = (const float*)d_in[10];
    const float* ctr2 = (const float*)d_in[11];

    char* ws = (char*)d_ws;
    unsigned*           cnt   = (unsigned*)(ws + CNT_OFF);
    unsigned*           tbin  = (unsigned*)(ws + TBIN_OFF);
    unsigned*           h16   = (unsigned*)(ws + H16_OFF);
    unsigned long long* list  = (unsigned long long*)(ws + LIST_OFF);
    unsigned*           candF = (unsigned*)(ws + CANDF_OFF);
    float*              candS = (float*)(ws + CANDS_OFF);
    float4*             dbox  = (float4*)(ws + DBOX_OFF);
    int*                dcls  = (int*)(ws + DCLS_OFF);
    float*              out   = (float*)d_out;

    hist_k<<<dim3(BPI, N_IMG), 256, 0, stream>>>(cls0, cls1, cls2, ctr0, ctr1, ctr2, h16);
    scan2_k<<<NPAIR, 256, 0, stream>>>(h16, tbin, cnt);
    compact_k<<<dim3(BPI, N_IMG), 256, 0, stream>>>(cls0, cls1, cls2, ctr0, ctr1, ctr2, tbin, cnt, list);
    sortmerge_k<<<NPAIR, 1024, 0, stream>>>(cnt, list, candF, candS);
    decode_k<<<(NPAIR * K_PRE + 255) / 256, 256, 0, stream>>>(
        loc0, loc1, loc2, reg0, reg1, reg2, candF, candS, dbox, dcls);
    nms_k<<<N_IMG, 1024, 0, stream>>>(dbox, dcls, candS, out);
}